// Round 1
// baseline (191.590 us; speedup 1.0000x reference)
//
#include <hip/hip_runtime.h>

#define BB 8
#define TT 2048
#define DD 128

// ---------------------------------------------------------------------------
// Kernel A: G[b] = enc[b]^T @ enc[b]  (128x128 Gram matrix per batch)
// Grid: (32 k-chunks, 8 batches), 256 threads.
// Each block: stage 64x128 enc tile in LDS, 8x8 register outer-product tile
// per thread, atomicAdd partials into G.
// ---------------------------------------------------------------------------
__global__ __launch_bounds__(256) void gram_kernel(const float* __restrict__ enc,
                                                   float* __restrict__ G) {
    const int b  = blockIdx.y;
    const int k0 = blockIdx.x * 64;
    const int t  = threadIdx.x;

    __shared__ __align__(16) float tile[64 * DD];  // [k][d], 32 KB

    const float* src = enc + (size_t)b * TT * DD + (size_t)k0 * DD;
    #pragma unroll
    for (int i = 0; i < 8; ++i) {
        ((float4*)tile)[i * 256 + t] = ((const float4*)src)[i * 256 + t];
    }
    __syncthreads();

    const int r0 = (t >> 4) * 8;   // rows of G this thread owns
    const int c0 = (t & 15) * 8;   // cols of G this thread owns

    float acc[8][8];
    #pragma unroll
    for (int i = 0; i < 8; ++i)
        #pragma unroll
        for (int j = 0; j < 8; ++j) acc[i][j] = 0.0f;

    #pragma unroll 2
    for (int k = 0; k < 64; ++k) {
        const float4 ra = *(const float4*)&tile[k * DD + r0];
        const float4 rb = *(const float4*)&tile[k * DD + r0 + 4];
        const float4 ca = *(const float4*)&tile[k * DD + c0];
        const float4 cb = *(const float4*)&tile[k * DD + c0 + 4];
        const float er[8] = {ra.x, ra.y, ra.z, ra.w, rb.x, rb.y, rb.z, rb.w};
        const float ec[8] = {ca.x, ca.y, ca.z, ca.w, cb.x, cb.y, cb.z, cb.w};
        #pragma unroll
        for (int i = 0; i < 8; ++i)
            #pragma unroll
            for (int j = 0; j < 8; ++j)
                acc[i][j] += er[i] * ec[j];
    }

    float* Gb = G + b * (DD * DD);
    #pragma unroll
    for (int i = 0; i < 8; ++i)
        #pragma unroll
        for (int j = 0; j < 8; ++j)
            atomicAdd(&Gb[(r0 + i) * DD + (c0 + j)], acc[i][j]);
}

// ---------------------------------------------------------------------------
// Kernel B: out[b] = dec[b] @ G[b]
// Grid: (32 q-chunks, 2 d-chunks, 8 batches), 256 threads.
// Block tile: 64 q x 64 d. G column-block (128x64) + dec tile (64x128) in LDS.
// Each thread: 4 q x 4 d outputs, float4 math.
// ---------------------------------------------------------------------------
__global__ __launch_bounds__(256) void apply_kernel(const float* __restrict__ dec,
                                                    const float* __restrict__ G,
                                                    float* __restrict__ out) {
    const int b   = blockIdx.z;
    const int q0  = blockIdx.x * 64;
    const int d0b = blockIdx.y * 64;
    const int t   = threadIdx.x;

    __shared__ __align__(16) float Gs[DD * 64];  // [c][d_local], 32 KB
    __shared__ __align__(16) float Ds[64 * DD];  // [q_local][c], 32 KB

    // Stage G: Gs[c][dl] = G[b][c][d0b+dl]; 2048 float4 total, 8 per thread.
    const float* Gb = G + b * DD * DD;
    #pragma unroll
    for (int i = 0; i < 8; ++i) {
        const int f4  = i * 256 + t;   // float4 index, row = f4/16, col4 = f4%16
        const int c   = f4 >> 4;
        const int dl4 = f4 & 15;
        ((float4*)Gs)[f4] = ((const float4*)(Gb + c * DD + d0b))[dl4];
    }

    // Stage dec tile: 64 rows x 128 cols, contiguous.
    const float* decb = dec + (size_t)b * TT * DD + (size_t)q0 * DD;
    #pragma unroll
    for (int i = 0; i < 8; ++i) {
        ((float4*)Ds)[i * 256 + t] = ((const float4*)decb)[i * 256 + t];
    }
    __syncthreads();

    const int dl = (t & 15) * 4;   // local d offset (0..60)
    const int qb = (t >> 4) * 4;   // local q base (0..60)

    float4 acc[4];
    #pragma unroll
    for (int i = 0; i < 4; ++i) acc[i] = make_float4(0.f, 0.f, 0.f, 0.f);

    #pragma unroll 2
    for (int c = 0; c < DD; c += 4) {
        const float4 g0 = *(const float4*)&Gs[(c + 0) * 64 + dl];
        const float4 g1 = *(const float4*)&Gs[(c + 1) * 64 + dl];
        const float4 g2 = *(const float4*)&Gs[(c + 2) * 64 + dl];
        const float4 g3 = *(const float4*)&Gs[(c + 3) * 64 + dl];
        #pragma unroll
        for (int i = 0; i < 4; ++i) {
            const float4 dv = *(const float4*)&Ds[(qb + i) * DD + c];
            acc[i].x += dv.x * g0.x + dv.y * g1.x + dv.z * g2.x + dv.w * g3.x;
            acc[i].y += dv.x * g0.y + dv.y * g1.y + dv.z * g2.y + dv.w * g3.y;
            acc[i].z += dv.x * g0.z + dv.y * g1.z + dv.z * g2.z + dv.w * g3.z;
            acc[i].w += dv.x * g0.w + dv.y * g1.w + dv.z * g2.w + dv.w * g3.w;
        }
    }

    float* ob = out + (size_t)b * TT * DD + (size_t)q0 * DD + d0b;
    #pragma unroll
    for (int i = 0; i < 4; ++i) {
        *(float4*)&ob[(qb + i) * DD + dl] = acc[i];
    }
}

extern "C" void kernel_launch(void* const* d_in, const int* in_sizes, int n_in,
                              void* d_out, int out_size, void* d_ws, size_t ws_size,
                              hipStream_t stream) {
    const float* enc = (const float*)d_in[0];  // encoder_hidden_states (8,2048,128)
    const float* dec = (const float*)d_in[1];  // decoder_hidden_states (8,2048,128)
    float* out = (float*)d_out;                // (8,2048,128) fp32
    float* G   = (float*)d_ws;                 // 8 x 128 x 128 fp32 = 512 KB

    // Zero the Gram accumulator (ws is re-poisoned to 0xAA before every call).
    hipMemsetAsync(G, 0, (size_t)BB * DD * DD * sizeof(float), stream);

    dim3 gridA(32, BB);
    gram_kernel<<<gridA, 256, 0, stream>>>(enc, G);

    dim3 gridB(32, 2, BB);
    apply_kernel<<<gridB, 256, 0, stream>>>(dec, G, out);
}

// Round 2
// 99.857 us; speedup vs baseline: 1.9186x; 1.9186x over previous
//
#include <hip/hip_runtime.h>

#define BB 8
#define TT 2048
#define DD 128

// ---------------------------------------------------------------------------
// Kernel A: partial Gram. P[chunk][b] = enc[b][chunk-rows]^T @ enc[b][chunk-rows]
// Grid: (CH chunks, BB batches), 256 threads. NO atomics — each block writes
// its own 128x128 partial to workspace.
// ---------------------------------------------------------------------------
__global__ __launch_bounds__(256) void gram_partial(const float* __restrict__ enc,
                                                    float* __restrict__ P,
                                                    int CH) {
    const int b     = blockIdx.y;
    const int chunk = blockIdx.x;
    const int t     = threadIdx.x;
    const int rowsPer = TT / CH;
    const int NT      = rowsPer / 64;

    __shared__ __align__(16) float tile[64 * DD];  // [k][d], 32 KB

    const int r0 = (t >> 4) * 8;   // rows of G this thread owns
    const int c0 = (t & 15) * 8;   // cols of G this thread owns

    float acc[8][8];
    #pragma unroll
    for (int i = 0; i < 8; ++i)
        #pragma unroll
        for (int j = 0; j < 8; ++j) acc[i][j] = 0.0f;

    for (int tt = 0; tt < NT; ++tt) {
        const float* src = enc + ((size_t)b * TT + (size_t)chunk * rowsPer + tt * 64) * DD;
        __syncthreads();  // protect tile from previous iteration's readers
        #pragma unroll
        for (int i = 0; i < 8; ++i) {
            ((float4*)tile)[i * 256 + t] = ((const float4*)src)[i * 256 + t];
        }
        __syncthreads();

        #pragma unroll 4
        for (int k = 0; k < 64; ++k) {
            const float4 ra = *(const float4*)&tile[k * DD + r0];
            const float4 rb = *(const float4*)&tile[k * DD + r0 + 4];
            const float4 ca = *(const float4*)&tile[k * DD + c0];
            const float4 cb = *(const float4*)&tile[k * DD + c0 + 4];
            const float er[8] = {ra.x, ra.y, ra.z, ra.w, rb.x, rb.y, rb.z, rb.w};
            const float ec[8] = {ca.x, ca.y, ca.z, ca.w, cb.x, cb.y, cb.z, cb.w};
            #pragma unroll
            for (int i = 0; i < 8; ++i)
                #pragma unroll
                for (int j = 0; j < 8; ++j)
                    acc[i][j] += er[i] * ec[j];
        }
    }

    float* Pb = P + ((size_t)chunk * BB + b) * (DD * DD);
    #pragma unroll
    for (int i = 0; i < 8; ++i) {
        #pragma unroll
        for (int j = 0; j < 2; ++j) {
            float4 v = make_float4(acc[i][j * 4 + 0], acc[i][j * 4 + 1],
                                   acc[i][j * 4 + 2], acc[i][j * 4 + 3]);
            *(float4*)&Pb[(r0 + i) * DD + c0 + j * 4] = v;
        }
    }
}

// ---------------------------------------------------------------------------
// Kernel A2: G = sum over chunks of P. 32768 float4 outputs, 128 blocks.
// ---------------------------------------------------------------------------
__global__ __launch_bounds__(256) void gram_reduce(const float* __restrict__ P,
                                                   float* __restrict__ G,
                                                   int CH) {
    const int g = blockIdx.x * 256 + threadIdx.x;   // float4 index into G (b*4096 + e4)
    const float4* Pf = (const float4*)P;
    float4 s = make_float4(0.f, 0.f, 0.f, 0.f);
    const int stride = BB * (DD * DD / 4);          // float4 stride between chunks
    for (int c = 0; c < CH; ++c) {
        const float4 v = Pf[(size_t)c * stride + g];
        s.x += v.x; s.y += v.y; s.z += v.z; s.w += v.w;
    }
    ((float4*)G)[g] = s;
}

// ---------------------------------------------------------------------------
// Kernel B: out[b] = dec[b] @ G[b]
// Grid: (32 q-chunks, 2 d-chunks, 8 batches), 256 threads.
// Ds padded to stride 132 floats: bank offset per q-row = 4*q mod 32 → the
// four reading quads (qb = 0,4,8,12) land on 2-way-aliased banks (free).
// ---------------------------------------------------------------------------
#define DS_STRIDE 132

__global__ __launch_bounds__(256) void apply_kernel(const float* __restrict__ dec,
                                                    const float* __restrict__ G,
                                                    float* __restrict__ out) {
    const int b   = blockIdx.z;
    const int q0  = blockIdx.x * 64;
    const int d0b = blockIdx.y * 64;
    const int t   = threadIdx.x;

    __shared__ __align__(16) float Gs[DD * 64];          // [c][d_local], 32 KB
    __shared__ __align__(16) float Ds[64 * DS_STRIDE];   // [q_local][c] padded, 33 KB

    // Stage G: Gs[c][dl] = G[b][c][d0b+dl]
    const float* Gb = G + b * DD * DD;
    #pragma unroll
    for (int i = 0; i < 8; ++i) {
        const int f4  = i * 256 + t;
        const int c   = f4 >> 4;
        const int dl4 = f4 & 15;
        ((float4*)Gs)[f4] = ((const float4*)(Gb + c * DD + d0b))[dl4];
    }

    // Stage dec tile (64 x 128, contiguous source) into padded LDS.
    const float* decb = dec + (size_t)b * TT * DD + (size_t)q0 * DD;
    #pragma unroll
    for (int i = 0; i < 8; ++i) {
        const int f4   = i * 256 + t;
        const int row  = f4 >> 5;   // 32 float4 per source row
        const int col4 = f4 & 31;
        ((float4*)Ds)[row * (DS_STRIDE / 4) + col4] = ((const float4*)decb)[f4];
    }
    __syncthreads();

    const int dl = (t & 15) * 4;   // local d offset (0..60)
    const int qb = (t >> 4) * 4;   // local q base (0..12) within wave; 0..60 over block

    float4 acc[4];
    #pragma unroll
    for (int i = 0; i < 4; ++i) acc[i] = make_float4(0.f, 0.f, 0.f, 0.f);

    #pragma unroll 8
    for (int c = 0; c < DD; c += 4) {
        const float4 g0 = *(const float4*)&Gs[(c + 0) * 64 + dl];
        const float4 g1 = *(const float4*)&Gs[(c + 1) * 64 + dl];
        const float4 g2 = *(const float4*)&Gs[(c + 2) * 64 + dl];
        const float4 g3 = *(const float4*)&Gs[(c + 3) * 64 + dl];
        #pragma unroll
        for (int i = 0; i < 4; ++i) {
            const float4 dv = *(const float4*)&Ds[(qb + i) * DS_STRIDE + c];
            acc[i].x += dv.x * g0.x + dv.y * g1.x + dv.z * g2.x + dv.w * g3.x;
            acc[i].y += dv.x * g0.y + dv.y * g1.y + dv.z * g2.y + dv.w * g3.y;
            acc[i].z += dv.x * g0.z + dv.y * g1.z + dv.z * g2.z + dv.w * g3.z;
            acc[i].w += dv.x * g0.w + dv.y * g1.w + dv.z * g2.w + dv.w * g3.w;
        }
    }

    float* ob = out + (size_t)b * TT * DD + (size_t)q0 * DD + d0b;
    #pragma unroll
    for (int i = 0; i < 4; ++i) {
        *(float4*)&ob[(qb + i) * DD + dl] = acc[i];
    }
}

extern "C" void kernel_launch(void* const* d_in, const int* in_sizes, int n_in,
                              void* d_out, int out_size, void* d_ws, size_t ws_size,
                              hipStream_t stream) {
    const float* enc = (const float*)d_in[0];  // (8,2048,128) fp32
    const float* dec = (const float*)d_in[1];  // (8,2048,128) fp32
    float* out = (float*)d_out;                // (8,2048,128) fp32

    // Workspace layout: [ P: CH*8*128*128 fp32 partials ][ G: 8*128*128 fp32 ]
    const size_t gBytes = (size_t)BB * DD * DD * sizeof(float);       // 512 KB
    const size_t need32 = 32 * gBytes + gBytes;
    const size_t need16 = 16 * gBytes + gBytes;
    int CH = (ws_size >= need32) ? 32 : ((ws_size >= need16) ? 16 : 8);

    float* P = (float*)d_ws;
    float* G = P + (size_t)CH * BB * DD * DD;

    dim3 gridA(CH, BB);
    gram_partial<<<gridA, 256, 0, stream>>>(enc, P, CH);

    gram_reduce<<<BB * DD * DD / 4 / 256, 256, 0, stream>>>(P, G, CH);

    dim3 gridB(32, 2, BB);
    apply_kernel<<<gridB, 256, 0, stream>>>(dec, G, out);
}

// Round 3
// 96.424 us; speedup vs baseline: 1.9869x; 1.0356x over previous
//
#include <hip/hip_runtime.h>
#include <hip/hip_bf16.h>

#define BB 8
#define TT 2048
#define DD 128

static __device__ __forceinline__ float bf2f(unsigned short u) {
    union { unsigned int i; float f; } v;
    v.i = ((unsigned int)u) << 16;
    return v.f;
}

// ---------------------------------------------------------------------------
// Kernel A: partial Gram. P[chunk][b] = enc[b][chunk-rows]^T @ enc[b][chunk-rows]
// Partials stored as bf16 (storage rounding only; math fp32).
// Grid: (CH chunks, BB batches), 256 threads.
// __launch_bounds__(256,2): 256-VGPR budget so the 8x8 fp32 accumulator tile
// stays in VGPRs (bare launch_bounds(256) targeted 8 waves/EU -> 48 VGPRs ->
// accumulator spill, seen in R1 counters).
// ---------------------------------------------------------------------------
__global__ __launch_bounds__(256, 2) void gram_partial(const float* __restrict__ enc,
                                                       __hip_bfloat16* __restrict__ P,
                                                       int CH) {
    const int b     = blockIdx.y;
    const int chunk = blockIdx.x;
    const int t     = threadIdx.x;
    const int rowsPer = TT / CH;
    const int NT      = rowsPer / 64;

    __shared__ __align__(16) float tile[64 * DD];  // [k][d], 32 KB

    const int r0 = (t >> 4) * 8;   // rows of G this thread owns
    const int c0 = (t & 15) * 8;   // cols of G this thread owns

    float acc[8][8];
    #pragma unroll
    for (int i = 0; i < 8; ++i)
        #pragma unroll
        for (int j = 0; j < 8; ++j) acc[i][j] = 0.0f;

    for (int tt = 0; tt < NT; ++tt) {
        const float* src = enc + ((size_t)b * TT + (size_t)chunk * rowsPer + tt * 64) * DD;
        __syncthreads();
        #pragma unroll
        for (int i = 0; i < 8; ++i) {
            ((float4*)tile)[i * 256 + t] = ((const float4*)src)[i * 256 + t];
        }
        __syncthreads();

        #pragma unroll 4
        for (int k = 0; k < 64; ++k) {
            const float4 ra = *(const float4*)&tile[k * DD + r0];
            const float4 rb = *(const float4*)&tile[k * DD + r0 + 4];
            const float4 ca = *(const float4*)&tile[k * DD + c0];
            const float4 cb = *(const float4*)&tile[k * DD + c0 + 4];
            const float er[8] = {ra.x, ra.y, ra.z, ra.w, rb.x, rb.y, rb.z, rb.w};
            const float ec[8] = {ca.x, ca.y, ca.z, ca.w, cb.x, cb.y, cb.z, cb.w};
            #pragma unroll
            for (int i = 0; i < 8; ++i)
                #pragma unroll
                for (int j = 0; j < 8; ++j)
                    acc[i][j] += er[i] * ec[j];
        }
    }

    __hip_bfloat16* Pb = P + ((size_t)chunk * BB + b) * (DD * DD);
    #pragma unroll
    for (int i = 0; i < 8; ++i) {
        __hip_bfloat16 row[8];
        #pragma unroll
        for (int j = 0; j < 8; ++j) row[j] = __float2bfloat16(acc[i][j]);
        *(uint4*)&Pb[(r0 + i) * DD + c0] = *(uint4*)row;   // 16B store of 8 bf16
    }
}

// ---------------------------------------------------------------------------
// Kernel A2: G = sum over chunks of P (bf16 partials -> fp32 G).
// 32768 float4 outputs, 128 blocks x 256 threads.
// ---------------------------------------------------------------------------
__global__ __launch_bounds__(256) void gram_reduce(const __hip_bfloat16* __restrict__ P,
                                                   float* __restrict__ G,
                                                   int CH) {
    const int g = blockIdx.x * 256 + threadIdx.x;   // 4-element group index into G
    const ushort4* Pu = (const ushort4*)P;
    const int stride = BB * DD * DD / 4;            // ushort4 groups per chunk
    float4 s = make_float4(0.f, 0.f, 0.f, 0.f);
    for (int c = 0; c < CH; ++c) {
        const ushort4 v = Pu[(size_t)c * stride + g];
        s.x += bf2f(v.x); s.y += bf2f(v.y); s.z += bf2f(v.z); s.w += bf2f(v.w);
    }
    ((float4*)G)[g] = s;
}

// ---------------------------------------------------------------------------
// Kernel B: out[b] = dec[b] @ G[b]
// Grid: (32 q-chunks, 2 d-chunks, 8 batches), 256 threads, 64q x 64d tile.
// Ds padded to stride 132 to keep dec reads off power-of-2 banks.
// ---------------------------------------------------------------------------
#define DS_STRIDE 132

__global__ __launch_bounds__(256, 2) void apply_kernel(const float* __restrict__ dec,
                                                       const float* __restrict__ G,
                                                       float* __restrict__ out) {
    const int b   = blockIdx.z;
    const int q0  = blockIdx.x * 64;
    const int d0b = blockIdx.y * 64;
    const int t   = threadIdx.x;

    __shared__ __align__(16) float Gs[DD * 64];          // [c][d_local], 32 KB
    __shared__ __align__(16) float Ds[64 * DS_STRIDE];   // [q_local][c] padded, 33 KB

    const float* Gb = G + b * DD * DD;
    #pragma unroll
    for (int i = 0; i < 8; ++i) {
        const int f4  = i * 256 + t;
        const int c   = f4 >> 4;
        const int dl4 = f4 & 15;
        ((float4*)Gs)[f4] = ((const float4*)(Gb + c * DD + d0b))[dl4];
    }

    const float* decb = dec + (size_t)b * TT * DD + (size_t)q0 * DD;
    #pragma unroll
    for (int i = 0; i < 8; ++i) {
        const int f4   = i * 256 + t;
        const int row  = f4 >> 5;   // 32 float4 per source row
        const int col4 = f4 & 31;
        ((float4*)Ds)[row * (DS_STRIDE / 4) + col4] = ((const float4*)decb)[f4];
    }
    __syncthreads();

    const int dl = (t & 15) * 4;   // local d offset (0..60)
    const int qb = (t >> 4) * 4;   // local q base (0..60)

    float4 acc[4];
    #pragma unroll
    for (int i = 0; i < 4; ++i) acc[i] = make_float4(0.f, 0.f, 0.f, 0.f);

    #pragma unroll 8
    for (int c = 0; c < DD; c += 4) {
        const float4 g0 = *(const float4*)&Gs[(c + 0) * 64 + dl];
        const float4 g1 = *(const float4*)&Gs[(c + 1) * 64 + dl];
        const float4 g2 = *(const float4*)&Gs[(c + 2) * 64 + dl];
        const float4 g3 = *(const float4*)&Gs[(c + 3) * 64 + dl];
        #pragma unroll
        for (int i = 0; i < 4; ++i) {
            const float4 dv = *(const float4*)&Ds[(qb + i) * DS_STRIDE + c];
            acc[i].x += dv.x * g0.x + dv.y * g1.x + dv.z * g2.x + dv.w * g3.x;
            acc[i].y += dv.x * g0.y + dv.y * g1.y + dv.z * g2.y + dv.w * g3.y;
            acc[i].z += dv.x * g0.z + dv.y * g1.z + dv.z * g2.z + dv.w * g3.z;
            acc[i].w += dv.x * g0.w + dv.y * g1.w + dv.z * g2.w + dv.w * g3.w;
        }
    }

    float* ob = out + (size_t)b * TT * DD + (size_t)q0 * DD + d0b;
    #pragma unroll
    for (int i = 0; i < 4; ++i) {
        *(float4*)&ob[(qb + i) * DD + dl] = acc[i];
    }
}

extern "C" void kernel_launch(void* const* d_in, const int* in_sizes, int n_in,
                              void* d_out, int out_size, void* d_ws, size_t ws_size,
                              hipStream_t stream) {
    const float* enc = (const float*)d_in[0];  // (8,2048,128) fp32
    const float* dec = (const float*)d_in[1];  // (8,2048,128) fp32
    float* out = (float*)d_out;                // (8,2048,128) fp32

    // Workspace layout: [ P: CH*8*128*128 bf16 partials ][ G: 8*128*128 fp32 ]
    const size_t pChunkBytes = (size_t)BB * DD * DD * sizeof(__hip_bfloat16);  // 256 KB
    const size_t gBytes      = (size_t)BB * DD * DD * sizeof(float);           // 512 KB
    int CH = 32;
    if (ws_size < 32 * pChunkBytes + gBytes) CH = 16;
    if (ws_size < 16 * pChunkBytes + gBytes) CH = 8;

    __hip_bfloat16* P = (__hip_bfloat16*)d_ws;
    float* G = (float*)((char*)d_ws + (size_t)CH * pChunkBytes);

    dim3 gridA(CH, BB);
    gram_partial<<<gridA, 256, 0, stream>>>(enc, P, CH);

    gram_reduce<<<BB * DD * DD / 4 / 256, 256, 0, stream>>>(P, G, CH);

    dim3 gridB(32, 2, BB);
    apply_kernel<<<gridB, 256, 0, stream>>>(dec, G, out);
}